// Round 3
// baseline (215.327 us; speedup 1.0000x reference)
//
#include <hip/hip_runtime.h>
#include <hip/hip_bf16.h>

namespace {

constexpr int BB  = 8;
constexpr int CC  = 256;
constexpr int NN  = 4096;
constexpr int CPG = 16;
constexpr float EPS_GN = 1e-6f;
constexpr float EPS_L2 = 1e-12f;

typedef __attribute__((ext_vector_type(8))) short bf16x8;
typedef __attribute__((ext_vector_type(4))) float f32x4;
typedef __attribute__((ext_vector_type(4))) unsigned short u16x4;

__device__ __forceinline__ unsigned short f2bf(float f) {
  union { __hip_bfloat16 h; unsigned short u; } cv;
  cv.h = __float2bfloat16(f);
  return cv.u;
}

// ---------------- weight f32 -> bf16 ----------------
__global__ __launch_bounds__(256) void cvt_bf_k(const float* __restrict__ src,
                                                unsigned short* __restrict__ dst, int n4) {
  int i = blockIdx.x * 256 + threadIdx.x;
  if (i < n4) {
    float4 v = ((const float4*)src)[i];
    u16x4 o;
    o.x = f2bf(v.x); o.y = f2bf(v.y); o.z = f2bf(v.z); o.w = f2bf(v.w);
    ((u16x4*)dst)[i] = o;
  }
}

// ---------------- GroupNorm stats: one block per (b,g) ----------------
__global__ __launch_bounds__(256) void gn_stats_k(const float* __restrict__ x,
                                                  float* __restrict__ stats) {
  int bg = blockIdx.x;
  const float4* base = (const float4*)(x + (size_t)bg * CPG * NN);
  float s = 0.f, ss = 0.f;
  for (int i = threadIdx.x; i < CPG * NN / 4; i += 256) {
    float4 v = base[i];
    s  += v.x + v.y + v.z + v.w;
    ss += v.x * v.x + v.y * v.y + v.z * v.z + v.w * v.w;
  }
#pragma unroll
  for (int off = 32; off; off >>= 1) {
    s  += __shfl_down(s, off);
    ss += __shfl_down(ss, off);
  }
  __shared__ float sh[8];
  int lane = threadIdx.x & 63, wid = threadIdx.x >> 6;
  if (lane == 0) { sh[wid] = s; sh[wid + 4] = ss; }
  __syncthreads();
  if (threadIdx.x == 0) {
    float S  = sh[0] + sh[1] + sh[2] + sh[3];
    float SS = sh[4] + sh[5] + sh[6] + sh[7];
    const float inv = 1.f / (float)(CPG * NN);
    float mean = S * inv;
    float var  = SS * inv - mean * mean;
    stats[bg * 2 + 0] = mean;
    stats[bg * 2 + 1] = rsqrtf(var + EPS_GN);
  }
}

// ---------------- GroupNorm apply + transpose: x (b,c,n) f32 -> gnxT (b,n,c) bf16 ----------------
__global__ __launch_bounds__(256) void gn_apply_t_k(const float* __restrict__ x,
                                                    const float* __restrict__ stats,
                                                    const float* __restrict__ gamma,
                                                    const float* __restrict__ beta,
                                                    unsigned short* __restrict__ gnxT) {
  __shared__ float tile[64][65];
  const int b = blockIdx.z, c0 = blockIdx.y * 64, n0 = blockIdx.x * 64;
  const int t = threadIdx.x;
  const float* xb = x + ((size_t)b << 20);
  const int cr = t >> 4, n4 = (t & 15) * 4;
#pragma unroll
  for (int p = 0; p < 4; ++p) {
    int c = cr + p * 16;
    float4 v = *(const float4*)(xb + (size_t)(c0 + c) * NN + n0 + n4);
    tile[c][n4 + 0] = v.x; tile[c][n4 + 1] = v.y;
    tile[c][n4 + 2] = v.z; tile[c][n4 + 3] = v.w;
  }
  __syncthreads();
  const int nr = t >> 4, c4 = (t & 15) * 4;
#pragma unroll
  for (int p = 0; p < 4; ++p) {
    int n = nr + p * 16;
    u16x4 pk;
#pragma unroll
    for (int k = 0; k < 4; ++k) {
      int c = c0 + c4 + k;
      int bg = b * 16 + (c >> 4);
      float ga = gamma[c] * stats[bg * 2 + 1];
      float be = beta[c] - stats[bg * 2 + 0] * ga;
      float v = tile[c4 + k][n] * ga + be;
      if (k == 0) pk.x = f2bf(v);
      else if (k == 1) pk.y = f2bf(v);
      else if (k == 2) pk.z = f2bf(v);
      else pk.w = f2bf(v);
    }
    *(u16x4*)(gnxT + ((size_t)b * NN + n0 + n) * CC + c0 + c4) = pk;
  }
}

// ---------------- L2 scales from bf16 Q/K rows ----------------
__global__ __launch_bounds__(256) void l2scale_bf_k(const unsigned short* __restrict__ qk,
                                                    float* __restrict__ scales) {
  const int row = blockIdx.x;  // b*512 + r (qk is [b][512][4096] contiguous)
  const int4* p = (const int4*)(qk + ((size_t)row << 12));
  float ss = 0.f;
  for (int i = threadIdx.x; i < 512; i += 256) {
    int4 v = p[i];
#pragma unroll
    for (int j2 = 0; j2 < 4; ++j2) {
      unsigned wv = (j2 == 0) ? (unsigned)v.x : (j2 == 1) ? (unsigned)v.y
                   : (j2 == 2) ? (unsigned)v.z : (unsigned)v.w;
      float f0 = __uint_as_float(wv << 16);
      float f1 = __uint_as_float(wv & 0xffff0000u);
      ss += f0 * f0 + f1 * f1;
    }
  }
#pragma unroll
  for (int off = 32; off; off >>= 1) ss += __shfl_down(ss, off);
  __shared__ float sh[4];
  int lane = threadIdx.x & 63, wid = threadIdx.x >> 6;
  if (lane == 0) sh[wid] = ss;
  __syncthreads();
  if (threadIdx.x == 0)
    scales[row] = 1.f / fmaxf(sqrtf(sh[0] + sh[1] + sh[2] + sh[3]), EPS_L2);
}

// ---------------- MFMA NT-GEMM: C[m][n] = sum_k A[m][k] * B[n][k] ----------------
// 128x128 tile, BK=64, 256 threads (4 waves, 2x2), 4x4 fragments of 16x16x32.
// MODE 0: QKV   (bias; m<512 -> bf16 [m][n]; m>=512 -> bf16 transposed [n][m-512])
// MODE 1: attn  (split-K partials, f32 [slice][m][n] direct)
// MODE 2: PV    (bf16 transposed [n][m])
// MODE 3: proj  (bias + residual, f32 [m][n] direct)
// bf16 outputs are staged through LDS (swizzled) and written as coalesced dwordx4.
template <int MODE>
__global__ __launch_bounds__(256) void mfma_nt_k(
    const unsigned short* __restrict__ A, long abst, int lda,
    const unsigned short* __restrict__ B, long bbst, int ldb,
    int K, int KS,
    const float* __restrict__ bias, const float* __restrict__ resid,
    float* __restrict__ outF, unsigned short* __restrict__ outU0,
    unsigned short* __restrict__ outU1) {
  __shared__ char shmem[32768];
  unsigned short* As = (unsigned short*)shmem;          // 128x64
  unsigned short* Bs = (unsigned short*)(shmem + 16384);// 128x64
  const int z = blockIdx.z;
  const int b = z / KS, sl = z % KS;
  const int kper = K / KS;
  const unsigned short* Ab = A + (size_t)b * abst;
  const unsigned short* Bb = B + (size_t)b * bbst;
  const int m0 = blockIdx.y * 128, n0 = blockIdx.x * 128;
  const int tid = threadIdx.x;
  const int l = tid & 63, w = tid >> 6;
  const int wm = w >> 1, wn = w & 1;

  // staging: thread t loads 64B (4 x 16B chunks) of one row-half; XOR-swizzled LDS slot
  const int sr = tid >> 1;
  const int sb = (tid & 1) * 4;
  const unsigned short* aG = Ab + (size_t)(m0 + sr) * lda + (size_t)sl * kper + sb * 8;
  const unsigned short* bG = Bb + (size_t)(n0 + sr) * ldb + (size_t)sl * kper + sb * 8;
  int wOff[4];
#pragma unroll
  for (int c = 0; c < 4; ++c)
    wOff[c] = sr * 128 + (((sb + c) ^ (sr & 7)) << 4);

  // fragment read offsets (kk=0); kk=1 differs by XOR 0x40
  int rdA[4], rdB[4];
#pragma unroll
  for (int i = 0; i < 4; ++i) {
    int rm = wm * 64 + i * 16 + (l & 15);
    rdA[i] = rm * 128 + ((((l >> 4)) ^ (l & 7)) << 4);
    int rn = wn * 64 + i * 16 + (l & 15);
    rdB[i] = rn * 128 + ((((l >> 4)) ^ (l & 7)) << 4);
  }

  f32x4 zero = {0.f, 0.f, 0.f, 0.f};
  f32x4 acc[4][4];
#pragma unroll
  for (int i = 0; i < 4; ++i)
#pragma unroll
    for (int j = 0; j < 4; ++j) acc[i][j] = zero;

  const int ksteps = kper / 64;
  for (int ks = 0; ks < ksteps; ++ks) {
    int4 av[4], bv[4];
#pragma unroll
    for (int c = 0; c < 4; ++c) {
      av[c] = *(const int4*)(aG + c * 8);
      bv[c] = *(const int4*)(bG + c * 8);
    }
    aG += 64; bG += 64;
    __syncthreads();
#pragma unroll
    for (int c = 0; c < 4; ++c) {
      *(int4*)((char*)As + wOff[c]) = av[c];
      *(int4*)((char*)Bs + wOff[c]) = bv[c];
    }
    __syncthreads();
#pragma unroll
    for (int kk = 0; kk < 2; ++kk) {
      bf16x8 af[4], bfr[4];
#pragma unroll
      for (int i = 0; i < 4; ++i) {
        af[i]  = *(const bf16x8*)((const char*)As + (rdA[i] ^ (kk << 6)));
        bfr[i] = *(const bf16x8*)((const char*)Bs + (rdB[i] ^ (kk << 6)));
      }
#pragma unroll
      for (int i = 0; i < 4; ++i)
#pragma unroll
        for (int j = 0; j < 4; ++j)
          acc[i][j] = __builtin_amdgcn_mfma_f32_16x16x32_bf16(af[i], bfr[j], acc[i][j], 0, 0, 0);
    }
  }

  // D layout per 16x16 frag: col = l&15, row = (l>>4)*4 + r
  const int mloc = wm * 64 + ((l >> 4) << 2);   // m-local base (row of fragment)
  const int nloc = wn * 64 + (l & 15);          // n-local base (col of fragment)

  if (MODE == 1) {
    const int mB = m0 + mloc, nB = n0 + nloc;
    float* po = outF + (size_t)(b * KS + sl) * 65536;
#pragma unroll
    for (int i = 0; i < 4; ++i)
#pragma unroll
      for (int r = 0; r < 4; ++r)
#pragma unroll
        for (int j = 0; j < 4; ++j)
          po[(size_t)(mB + i * 16 + r) * 256 + nB + j * 16] = acc[i][j][r];
    return;
  }
  if (MODE == 3) {
    const int mB = m0 + mloc, nB = n0 + nloc;
#pragma unroll
    for (int i = 0; i < 4; ++i) {
      int mI = mB + i * 16;
#pragma unroll
      for (int r = 0; r < 4; ++r) {
        float bv_ = bias[mI + r];
        size_t rowo = ((size_t)b << 20) + (size_t)(mI + r) * 4096;
#pragma unroll
        for (int j = 0; j < 4; ++j)
          outF[rowo + nB + j * 16] = acc[i][j][r] + bv_ + resid[rowo + nB + j * 16];
      }
    }
    return;
  }

  // ---- bf16 epilogue via LDS (coalesced stores) ----
  __syncthreads();  // all waves done reading As/Bs
  unsigned short* Cs = (unsigned short*)shmem;  // 128x128 bf16 = 32KB

  const bool qkreg = (MODE == 0) && (m0 < 512);
  if (qkreg) {
    // LDS[row=m_local][col=n_local], bias on m
#pragma unroll
    for (int i = 0; i < 4; ++i) {
#pragma unroll
      for (int r = 0; r < 4; ++r) {
        int row = mloc + i * 16 + r;
        float bv_ = bias[m0 + row];
#pragma unroll
        for (int j = 0; j < 4; ++j) {
          int col = nloc + j * 16;
          int byte = (row << 8) + (col << 1);
          byte ^= (row & 15) << 4;
          *(unsigned short*)((char*)Cs + byte) = f2bf(acc[i][j][r] + bv_);
        }
      }
    }
  } else {
    // LDS[row=n_local][col=m_local] (transposed), optional bias on m
#pragma unroll
    for (int i = 0; i < 4; ++i) {
      float bb4[4];
#pragma unroll
      for (int r = 0; r < 4; ++r)
        bb4[r] = (MODE == 0) ? bias[m0 + mloc + i * 16 + r] : 0.f;
#pragma unroll
      for (int j = 0; j < 4; ++j) {
        int row = nloc + j * 16;
        int rowswz = (row & 15) << 4;
#pragma unroll
        for (int r = 0; r < 4; ++r) {
          int col = mloc + i * 16 + r;
          int byte = (row << 8) + (col << 1);
          byte ^= rowswz;
          *(unsigned short*)((char*)Cs + byte) = f2bf(acc[i][j][r] + bb4[r]);
        }
      }
    }
  }
  __syncthreads();

  // readout: thread t -> LDS row t>>1, half t&1 (128B = 8 x 16B)
  const int rr = tid >> 1, hh = tid & 1;
  int4 vv[8];
#pragma unroll
  for (int k = 0; k < 8; ++k) {
    int byte = (rr << 8) + (hh << 7) + (k << 4);
    byte ^= (rr & 15) << 4;
    vv[k] = *(const int4*)((const char*)Cs + byte);
  }
  if (qkreg) {
    unsigned short* dst = outU0 + (size_t)b * (512 * 4096) +
                          (size_t)(m0 + rr) * 4096 + n0 + hh * 64;
#pragma unroll
    for (int k = 0; k < 8; ++k) *(int4*)(dst + k * 8) = vv[k];
  } else {
    const int mbase = (MODE == 0) ? (m0 - 512) : m0;
    unsigned short* dst = outU1 + ((size_t)b * 4096 + n0 + rr) * 256 + mbase + hh * 64;
#pragma unroll
    for (int k = 0; k < 8; ++k) *(int4*)(dst + k * 8) = vv[k];
  }
}

// ---------------- reduce split-K partials + scale + softmax -> bf16 attn ----------------
__global__ __launch_bounds__(256) void attn_fix_k(const float* __restrict__ part,
                                                  const float* __restrict__ scales,
                                                  const float* __restrict__ temp,
                                                  unsigned short* __restrict__ attn_bf) {
  const int bc = blockIdx.x;  // b*256 + c
  const int b = bc >> 8, c = bc & 255;
  const int d = threadIdx.x;
  float v = 0.f;
#pragma unroll
  for (int s = 0; s < 8; ++s)
    v += part[((size_t)(b * 8 + s) << 16) + (c << 8) + d];
  v *= scales[b * 512 + c] * scales[b * 512 + 256 + d] * temp[0];
  float mx = v;
#pragma unroll
  for (int off = 32; off; off >>= 1) mx = fmaxf(mx, __shfl_xor(mx, off));
  __shared__ float sm[4], ssum[4];
  int lane = d & 63, wid = d >> 6;
  if (lane == 0) sm[wid] = mx;
  __syncthreads();
  mx = fmaxf(fmaxf(sm[0], sm[1]), fmaxf(sm[2], sm[3]));
  float e = expf(v - mx);
  float s = e;
#pragma unroll
  for (int off = 32; off; off >>= 1) s += __shfl_xor(s, off);
  if (lane == 0) ssum[wid] = s;
  __syncthreads();
  s = ssum[0] + ssum[1] + ssum[2] + ssum[3];
  attn_bf[((size_t)bc << 8) + d] = f2bf(e / s);
}

}  // namespace

extern "C" void kernel_launch(void* const* d_in, const int* in_sizes, int n_in,
                              void* d_out, int out_size, void* d_ws, size_t ws_size,
                              hipStream_t stream) {
  const float* x      = (const float*)d_in[0];
  const float* gamma  = (const float*)d_in[1];
  const float* beta   = (const float*)d_in[2];
  const float* qkv_w  = (const float*)d_in[3];
  const float* qkv_b  = (const float*)d_in[4];
  const float* temp   = (const float*)d_in[5];
  const float* proj_w = (const float*)d_in[6];
  const float* proj_b = (const float*)d_in[7];
  float* out = (float*)d_out;

  char* ws = (char*)d_ws;
  const size_t MB = 1048576;
  unsigned short* qkv_w_bf = (unsigned short*)(ws);                 // 0.4 MB
  unsigned short* proj_w_bf = (unsigned short*)(ws + 512 * 1024);   // 0.13 MB
  float* stats   = (float*)(ws + 0xA0000);
  float* scales  = (float*)(ws + 0xA1000);
  unsigned short* attn_bf = (unsigned short*)(ws + 1 * MB);         // 1 MB
  float* part    = (float*)(ws + 2 * MB);                           // 16 MB
  unsigned short* gnxT = (unsigned short*)(ws + 18 * MB);           // 16.8 MB
  unsigned short* qk   = (unsigned short*)(ws + 35 * MB);           // 33.6 MB
  unsigned short* vT   = (unsigned short*)(ws + 69 * MB);           // 16.8 MB
  unsigned short* pvT  = (unsigned short*)(ws + 86 * MB);           // 16.8 MB
  if (ws_size < 103 * MB) return;

  // weights -> bf16
  cvt_bf_k<<<192, 256, 0, stream>>>(qkv_w, qkv_w_bf, 768 * 256 / 4);
  cvt_bf_k<<<64, 256, 0, stream>>>(proj_w, proj_w_bf, 256 * 256 / 4);

  // GroupNorm -> gnxT (b, n, c) bf16
  gn_stats_k<<<128, 256, 0, stream>>>(x, stats);
  gn_apply_t_k<<<dim3(64, 4, 8), 256, 0, stream>>>(x, stats, gamma, beta, gnxT);

  // QKV: [768x256] @ [4096x256]^T per batch; Q/K -> qk (c-major), V -> vT (token-major)
  mfma_nt_k<0><<<dim3(32, 6, 8), 256, 0, stream>>>(
      qkv_w_bf, 0, 256, gnxT, (long)NN * CC, 256, 256, 1,
      qkv_b, nullptr, nullptr, qk, vT);

  // L2 scales over Q/K rows
  l2scale_bf_k<<<4096, 256, 0, stream>>>(qk, scales);

  // attn logits: Q @ K^T over K=4096, split-K=8 -> f32 partials
  mfma_nt_k<1><<<dim3(2, 2, 64), 256, 0, stream>>>(
      qk, (long)512 * 4096, 4096, qk + (size_t)256 * 4096, (long)512 * 4096, 4096,
      4096, 8, nullptr, nullptr, part, nullptr, nullptr);

  // reduce + scale + softmax -> bf16 attn
  attn_fix_k<<<2048, 256, 0, stream>>>(part, scales, temp, attn_bf);

  // PV: attn [256x256] @ vT [4096x256]^T -> pvT (token-major bf16)
  mfma_nt_k<2><<<dim3(32, 2, 8), 256, 0, stream>>>(
      attn_bf, (long)CC * CC, 256, vT, (long)NN * CC, 256, 256, 1,
      nullptr, nullptr, nullptr, nullptr, pvT);

  // proj + bias + residual -> out (f32)
  mfma_nt_k<3><<<dim3(32, 2, 8), 256, 0, stream>>>(
      proj_w_bf, 0, 256, pvT, (long)NN * CC, 256, 256, 1,
      proj_b, x, out, nullptr, nullptr);
}

// Round 4
// 132.107 us; speedup vs baseline: 1.6299x; 1.6299x over previous
//
#include <hip/hip_runtime.h>
#include <hip/hip_bf16.h>

namespace {

constexpr float EPS_GN = 1e-6f;
constexpr float EPS_L2 = 1e-12f;

typedef __attribute__((ext_vector_type(8))) short bf16x8;
typedef __attribute__((ext_vector_type(4))) float f32x4;

__device__ __forceinline__ unsigned short f2bf(float f) {
  union { __hip_bfloat16 h; unsigned short u; } cv;
  cv.h = __float2bfloat16(f);
  return cv.u;
}
__device__ __forceinline__ float blo(unsigned u) { return __uint_as_float(u << 16); }
__device__ __forceinline__ float bhi(unsigned u) { return __uint_as_float(u & 0xffff0000u); }

// ---------------- weights f32 -> bf16 ----------------
__global__ __launch_bounds__(256) void cvt_bf_k(const float* __restrict__ src,
                                                unsigned short* __restrict__ dst, int n4) {
  int i = blockIdx.x * 256 + threadIdx.x;
  if (i < n4) {
    float4 v = ((const float4*)src)[i];
    unsigned p0 = f2bf(v.x) | ((unsigned)f2bf(v.y) << 16);
    unsigned p1 = f2bf(v.z) | ((unsigned)f2bf(v.w) << 16);
    ((int2*)dst)[i] = make_int2((int)p0, (int)p1);
  }
}

// ---------------- 256x256 f32 -> transposed bf16 ----------------
__global__ __launch_bounds__(256) void cvt_t_k(const float* __restrict__ src,
                                               unsigned short* __restrict__ dst) {
  __shared__ float tl[64][65];
  const int j0 = blockIdx.y * 64, d0 = blockIdx.x * 64;
  const int t = threadIdx.x;
  const int jr = t >> 2, ds = (t & 3) * 16;
#pragma unroll
  for (int q = 0; q < 4; ++q) {
    float4 v = *(const float4*)(src + (size_t)(j0 + jr) * 256 + d0 + ds + q * 4);
    tl[jr][ds + q * 4 + 0] = v.x; tl[jr][ds + q * 4 + 1] = v.y;
    tl[jr][ds + q * 4 + 2] = v.z; tl[jr][ds + q * 4 + 3] = v.w;
  }
  __syncthreads();
  const int dr = t >> 2, js = (t & 3) * 16;
  unsigned pk[8];
#pragma unroll
  for (int q = 0; q < 8; ++q)
    pk[q] = f2bf(tl[js + 2 * q][dr]) | ((unsigned)f2bf(tl[js + 2 * q + 1][dr]) << 16);
  int4 o1 = make_int4((int)pk[0], (int)pk[1], (int)pk[2], (int)pk[3]);
  int4 o2 = make_int4((int)pk[4], (int)pk[5], (int)pk[6], (int)pk[7]);
  unsigned short* dp = dst + (size_t)(d0 + dr) * 256 + j0 + js;
  *(int4*)dp = o1;
  *(int4*)(dp + 8) = o2;
}

// ---------------- x -> xbf [b][c][n], xT [b][n][c], sx partials ----------------
__global__ __launch_bounds__(256) void xprep_k(const float* __restrict__ x,
                                               unsigned short* __restrict__ xbf,
                                               unsigned short* __restrict__ xT,
                                               float* __restrict__ sxpart) {
  __shared__ unsigned short tl[64][68];
  const int b = blockIdx.z, c0 = blockIdx.y * 64, n0 = blockIdx.x * 64;
  const int t = threadIdx.x;
  const int cl = t >> 2, ns = (t & 3) * 16;
  const float* xp = x + ((size_t)b << 20) + (size_t)(c0 + cl) * 4096 + n0 + ns;
  unsigned pk[8];
  float s = 0.f;
#pragma unroll
  for (int q = 0; q < 4; ++q) {
    float4 v = *(const float4*)(xp + q * 4);
    s += v.x + v.y + v.z + v.w;
    pk[2 * q + 0] = f2bf(v.x) | ((unsigned)f2bf(v.y) << 16);
    pk[2 * q + 1] = f2bf(v.z) | ((unsigned)f2bf(v.w) << 16);
  }
  unsigned short* xo = xbf + ((size_t)b << 20) + (size_t)(c0 + cl) * 4096 + n0 + ns;
  *(int4*)xo = make_int4((int)pk[0], (int)pk[1], (int)pk[2], (int)pk[3]);
  *(int4*)(xo + 8) = make_int4((int)pk[4], (int)pk[5], (int)pk[6], (int)pk[7]);
#pragma unroll
  for (int q = 0; q < 8; ++q)
    *(unsigned*)(&tl[cl][ns + 2 * q]) = pk[q];
  s += __shfl_xor(s, 1);
  s += __shfl_xor(s, 2);
  if ((t & 3) == 0)
    sxpart[((size_t)((b * 4 + blockIdx.y) * 64 + cl)) * 64 + blockIdx.x] = s;
  __syncthreads();
  const int nl = t >> 2, cs2 = (t & 3) * 16;
  unsigned pk2[8];
#pragma unroll
  for (int q = 0; q < 8; ++q)
    pk2[q] = (unsigned)(unsigned short)tl[cs2 + 2 * q][nl] |
             ((unsigned)(unsigned short)tl[cs2 + 2 * q + 1][nl] << 16);
  unsigned short* to = xT + ((size_t)((b << 12) + n0 + nl)) * 256 + c0 + cs2;
  *(int4*)to = make_int4((int)pk2[0], (int)pk2[1], (int)pk2[2], (int)pk2[3]);
  *(int4*)(to + 8) = make_int4((int)pk2[4], (int)pk2[5], (int)pk2[6], (int)pk2[7]);
}

// ---------------- generic 64x64-tile MFMA NT-GEMM ----------------
struct NTArgs {
  const unsigned short* A; long abst; int lda;
  const unsigned short* B; long bbst; int ldb;
  int K; int zdiv;
  float* outF; long ostF; int ldc;
  unsigned short* outU; long ostU;
  const float* qs; const float* wsv; const float* qkvb; const float* temp;
  const float* hvec; const float* xres;
};
enum { EPI_F32 = 0, EPI_BF16 = 1, EPI_LOGITS = 2, EPI_OUT = 3 };

template <int EPI>
__global__ __launch_bounds__(256) void nt64_k(NTArgs p) {
  __shared__ unsigned short As[4096];
  __shared__ unsigned short Bs[4096];
  const int z = blockIdx.z;
  const int b = z / p.zdiv, sl = z % p.zdiv;
  const int kper = p.K / p.zdiv;
  const int m0 = blockIdx.y * 64, n0 = blockIdx.x * 64;
  const int tid = threadIdx.x;
  const int l = tid & 63, w = tid >> 6;
  const int wm = w >> 1, wn = w & 1;

  const int r = tid >> 2;
  const unsigned short* aG = p.A + (size_t)b * p.abst + (size_t)(m0 + r) * p.lda +
                             (size_t)sl * kper + (tid & 3) * 16;
  const unsigned short* bG = p.B + (size_t)b * p.bbst + (size_t)(n0 + r) * p.ldb +
                             (size_t)sl * kper + (tid & 3) * 16;
  const int g0 = (tid & 3) * 2;
  const int w0 = r * 128 + (((g0)     ^ (r & 7)) << 4);
  const int w1 = r * 128 + (((g0 + 1) ^ (r & 7)) << 4);

  int rdA[2], rdB[2];
#pragma unroll
  for (int i = 0; i < 2; ++i) {
    int rm = wm * 32 + i * 16 + (l & 15);
    rdA[i] = rm * 128 + (((l >> 4) ^ (rm & 7)) << 4);
    int rn = wn * 32 + i * 16 + (l & 15);
    rdB[i] = rn * 128 + (((l >> 4) ^ (rn & 7)) << 4);
  }

  f32x4 zero = {0.f, 0.f, 0.f, 0.f};
  f32x4 acc[2][2] = {{zero, zero}, {zero, zero}};

  const int ksteps = kper >> 6;
  for (int ks = 0; ks < ksteps; ++ks) {
    int4 a0 = *(const int4*)aG, a1 = *(const int4*)(aG + 8);
    int4 b0 = *(const int4*)bG, b1 = *(const int4*)(bG + 8);
    aG += 64; bG += 64;
    __syncthreads();
    *(int4*)((char*)As + w0) = a0; *(int4*)((char*)As + w1) = a1;
    *(int4*)((char*)Bs + w0) = b0; *(int4*)((char*)Bs + w1) = b1;
    __syncthreads();
#pragma unroll
    for (int kk = 0; kk < 2; ++kk) {
      bf16x8 af[2], bf_[2];
#pragma unroll
      for (int i = 0; i < 2; ++i) {
        af[i]  = *(const bf16x8*)((const char*)As + (rdA[i] ^ (kk << 6)));
        bf_[i] = *(const bf16x8*)((const char*)Bs + (rdB[i] ^ (kk << 6)));
      }
#pragma unroll
      for (int i = 0; i < 2; ++i)
#pragma unroll
        for (int j = 0; j < 2; ++j)
          acc[i][j] = __builtin_amdgcn_mfma_f32_16x16x32_bf16(af[i], bf_[j], acc[i][j], 0, 0, 0);
    }
  }

  const int ml = wm * 32 + ((l >> 4) << 2);
  const int nl = wn * 32 + (l & 15);
  const int mB = m0 + ml, nB = n0 + nl;

  if (EPI == EPI_F32) {
    float* po = p.outF + (size_t)z * p.ostF;
#pragma unroll
    for (int i = 0; i < 2; ++i)
#pragma unroll
      for (int rr = 0; rr < 4; ++rr)
#pragma unroll
        for (int j = 0; j < 2; ++j)
          po[(size_t)(mB + i * 16 + rr) * p.ldc + nB + j * 16] = acc[i][j][rr];
  } else if (EPI == EPI_BF16) {
    unsigned short* pu = p.outU + (size_t)z * p.ostU;
#pragma unroll
    for (int i = 0; i < 2; ++i)
#pragma unroll
      for (int rr = 0; rr < 4; ++rr)
#pragma unroll
        for (int j = 0; j < 2; ++j)
          pu[(size_t)(mB + i * 16 + rr) * p.ldc + nB + j * 16] = f2bf(acc[i][j][rr]);
  } else if (EPI == EPI_LOGITS) {
    const float T = p.temp[0];
#pragma unroll
    for (int i = 0; i < 2; ++i) {
#pragma unroll
      for (int rr = 0; rr < 4; ++rr) {
        int mi = mB + i * 16 + rr;
        float qsv = p.qs[z * 512 + mi];
        float bq = p.qkvb[mi];
        float wqsv = p.wsv[z * 512 + mi];
#pragma unroll
        for (int j = 0; j < 2; ++j) {
          int nj = nB + j * 16;
          float ksv = p.qs[z * 512 + 256 + nj];
          float bk = p.qkvb[256 + nj];
          float wksv = p.wsv[z * 512 + 256 + nj];
          float v = acc[i][j][rr] + bq * wksv + bk * wqsv + 4096.f * bq * bk;
          p.outF[(size_t)z * p.ostF + (size_t)mi * p.ldc + nj] = T * qsv * ksv * v;
        }
      }
    }
  } else {  // EPI_OUT
#pragma unroll
    for (int i = 0; i < 2; ++i) {
#pragma unroll
      for (int rr = 0; rr < 4; ++rr) {
        int mi = mB + i * 16 + rr;
        float hv = p.hvec[z * 256 + mi];
        size_t rowo = ((size_t)z << 20) + (size_t)mi * 4096;
#pragma unroll
        for (int j = 0; j < 2; ++j)
          p.outF[rowo + nB + j * 16] =
              acc[i][j][rr] + hv + p.xres[rowo + nB + j * 16];
      }
    }
  }
}

// ---------------- GN stats + s + ws = [Wq;Wk] @ s ----------------
__global__ __launch_bounds__(256) void stats_k(
    const float* __restrict__ part, const float* __restrict__ sxpart,
    const float* __restrict__ gamma, const float* __restrict__ beta,
    const unsigned short* __restrict__ qkvw_bf,
    float* __restrict__ avec, float* __restrict__ evec,
    float* __restrict__ svec, float* __restrict__ sxvec,
    float* __restrict__ wsv) {
  const int b = blockIdx.x, c = threadIdx.x;
  const float* sp = sxpart + ((size_t)(b * 256 + c) << 6);
  float sxv = 0.f;
#pragma unroll 4
  for (int t = 0; t < 64; ++t) sxv += sp[t];
  float dg = 0.f;
#pragma unroll
  for (int s = 0; s < 4; ++s) dg += part[((size_t)(b * 4 + s) << 16) + c * 257];
  float gs = sxv, g2 = dg;
#pragma unroll
  for (int off = 1; off < 16; off <<= 1) {
    gs += __shfl_xor(gs, off);
    g2 += __shfl_xor(g2, off);
  }
  const float inv = 1.f / 65536.f;
  float mu = gs * inv;
  float var = g2 * inv - mu * mu;
  float rstd = rsqrtf(var + EPS_GN);
  float av = gamma[c] * rstd;
  float ev = beta[c] - mu * av;
  float sv = av * sxv + 4096.f * ev;
  avec[b * 256 + c] = av; evec[b * 256 + c] = ev;
  svec[b * 256 + c] = sv; sxvec[b * 256 + c] = sxv;
  __shared__ float sl_[256];
  sl_[c] = sv;
  __syncthreads();
  for (int i = c; i < 512; i += 256) {
    const unsigned short* wr = qkvw_bf + (size_t)i * 256;
    float acc = 0.f;
    for (int d = 0; d < 256; d += 8) {
      int4 v = *(const int4*)(wr + d);
      acc += blo((unsigned)v.x) * sl_[d + 0] + bhi((unsigned)v.x) * sl_[d + 1];
      acc += blo((unsigned)v.y) * sl_[d + 2] + bhi((unsigned)v.y) * sl_[d + 3];
      acc += blo((unsigned)v.z) * sl_[d + 4] + bhi((unsigned)v.z) * sl_[d + 5];
      acc += blo((unsigned)v.w) * sl_[d + 6] + bhi((unsigned)v.w) * sl_[d + 7];
    }
    wsv[b * 512 + i] = acc;
  }
}

// ---------------- G_bf from Sxx partials + a,e,sx ----------------
__global__ __launch_bounds__(256) void gfill_k(const float* __restrict__ part,
                                               const float* __restrict__ avec,
                                               const float* __restrict__ evec,
                                               const float* __restrict__ sxvec,
                                               unsigned short* __restrict__ Gbf) {
  const int b = blockIdx.y;
  const int r = blockIdx.x * 16 + (threadIdx.x >> 4);
  const int cs = (threadIdx.x & 15) * 16;
  const float ac = avec[b * 256 + r], ec = evec[b * 256 + r], sxc = sxvec[b * 256 + r];
  unsigned pk[8];
#pragma unroll
  for (int q = 0; q < 8; ++q) {
    unsigned lohi[2];
#pragma unroll
    for (int h = 0; h < 2; ++h) {
      int d = cs + 2 * q + h;
      float S = 0.f;
#pragma unroll
      for (int s = 0; s < 4; ++s)
        S += part[((size_t)(b * 4 + s) << 16) + r * 256 + d];
      float ad = avec[b * 256 + d], ed = evec[b * 256 + d], sxd = sxvec[b * 256 + d];
      float gv = ac * ad * S + ac * ed * sxc + ec * ad * sxd + 4096.f * ec * ed;
      lohi[h] = f2bf(gv);
    }
    pk[q] = lohi[0] | (lohi[1] << 16);
  }
  unsigned short* gp = Gbf + ((size_t)b << 16) + (size_t)r * 256 + cs;
  *(int4*)gp = make_int4((int)pk[0], (int)pk[1], (int)pk[2], (int)pk[3]);
  *(int4*)(gp + 8) = make_int4((int)pk[4], (int)pk[5], (int)pk[6], (int)pk[7]);
}

// ---------------- per-row l2 scales from U = [Wq;Wk]G ----------------
__global__ __launch_bounds__(256) void scales_k(const unsigned short* __restrict__ Ubf,
                                                const unsigned short* __restrict__ qkvw_bf,
                                                const float* __restrict__ qkv_b,
                                                const float* __restrict__ wsv,
                                                float* __restrict__ qsv) {
  const int row = blockIdx.x * 4 + (threadIdx.x >> 6);  // b*512 + i
  const int b = row >> 9, i = row & 511;
  const int l = threadIdx.x & 63;
  const unsigned short* ur = Ubf + ((size_t)b << 17) + (size_t)i * 256 + l * 4;
  const unsigned short* wr = qkvw_bf + (size_t)i * 256 + l * 4;
  int2 uv = *(const int2*)ur;
  int2 wv = *(const int2*)wr;
  float dot = blo((unsigned)uv.x) * blo((unsigned)wv.x) + bhi((unsigned)uv.x) * bhi((unsigned)wv.x) +
              blo((unsigned)uv.y) * blo((unsigned)wv.y) + bhi((unsigned)uv.y) * bhi((unsigned)wv.y);
#pragma unroll
  for (int off = 1; off < 64; off <<= 1) dot += __shfl_xor(dot, off);
  if (l == 0) {
    float bi = qkv_b[i], wsi = wsv[b * 512 + i];
    float n2 = dot + 2.f * bi * wsi + 4096.f * bi * bi;
    qsv[b * 512 + i] = 1.f / fmaxf(sqrtf(fmaxf(n2, 0.f)), EPS_L2);
  }
}

// ---------------- row softmax (256) -> bf16 ----------------
__global__ __launch_bounds__(256) void softmax_k(const float* __restrict__ logits,
                                                 unsigned short* __restrict__ Abf) {
  const int bc = blockIdx.x;
  const int j = threadIdx.x;
  float v = logits[((size_t)bc << 8) + j];
  float m = v;
#pragma unroll
  for (int off = 32; off; off >>= 1) m = fmaxf(m, __shfl_xor(m, off));
  __shared__ float sm[4], ssum[4];
  int lane = j & 63, wid = j >> 6;
  if (lane == 0) sm[wid] = m;
  __syncthreads();
  m = fmaxf(fmaxf(sm[0], sm[1]), fmaxf(sm[2], sm[3]));
  float e = expf(v - m);
  float s = e;
#pragma unroll
  for (int off = 32; off; off >>= 1) s += __shfl_xor(s, off);
  if (lane == 0) ssum[wid] = s;
  __syncthreads();
  s = ssum[0] + ssum[1] + ssum[2] + ssum[3];
  Abf[((size_t)bc << 8) + j] = f2bf(e / s);
}

// ---------------- finalize: F~ (bf16) and h~ ----------------
__global__ __launch_bounds__(256) void finalize_k(const unsigned short* __restrict__ Abf,
                                                  const float* __restrict__ FT,
                                                  const float* __restrict__ avec,
                                                  const float* __restrict__ evec,
                                                  const float* __restrict__ qkv_b,
                                                  const float* __restrict__ proj_w,
                                                  const float* __restrict__ proj_b,
                                                  unsigned short* __restrict__ Fbf,
                                                  float* __restrict__ hvec) {
  const int b = blockIdx.x, t = threadIdx.x;
  __shared__ float abv[256];
  const unsigned short* ar = Abf + ((size_t)b << 16) + (size_t)t * 256;
  float acc = 0.f;
  for (int j = 0; j < 256; j += 2) {
    unsigned u = *(const unsigned*)(ar + j);
    acc += blo(u) * qkv_b[512 + j] + bhi(u) * qkv_b[512 + j + 1];
  }
  abv[t] = acc;
  __syncthreads();
  float h = proj_b[t];
  const float* pr = proj_w + (size_t)t * 256;
  for (int i = 0; i < 256; ++i) h += pr[i] * abv[i];
  float hc2 = 0.f;
  for (int d = 0; d < 256; ++d) {
    float f = FT[((size_t)b << 16) + (size_t)d * 256 + t];
    hc2 += f * evec[b * 256 + d];
    Fbf[((size_t)b << 16) + (size_t)t * 256 + d] = f2bf(f * avec[b * 256 + d]);
  }
  hvec[b * 256 + t] = h + hc2;
}

}  // namespace

extern "C" void kernel_launch(void* const* d_in, const int* in_sizes, int n_in,
                              void* d_out, int out_size, void* d_ws, size_t ws_size,
                              hipStream_t stream) {
  const float* x      = (const float*)d_in[0];
  const float* gamma  = (const float*)d_in[1];
  const float* beta   = (const float*)d_in[2];
  const float* qkv_w  = (const float*)d_in[3];
  const float* qkv_b  = (const float*)d_in[4];
  const float* temp   = (const float*)d_in[5];
  const float* proj_w = (const float*)d_in[6];
  const float* proj_b = (const float*)d_in[7];
  float* out = (float*)d_out;

  char* ws = (char*)d_ws;
  const size_t MB = 1048576;
  unsigned short* qkvw_bf = (unsigned short*)(ws);             // 768x256 bf16 = 384KB
  unsigned short* pw_bf   = (unsigned short*)(ws + 0x60000);   // 128KB
  unsigned short* wvt_bf  = (unsigned short*)(ws + 0x80000);   // 128KB
  float* avec   = (float*)(ws + 0xA0000);   // 8x256
  float* evec   = (float*)(ws + 0xA2000);
  float* svec   = (float*)(ws + 0xA4000);
  float* sxvec  = (float*)(ws + 0xA6000);
  float* wsv    = (float*)(ws + 0xA8000);   // 8x512
  float* qsv    = (float*)(ws + 0xAC000);   // 8x512
  float* hvec   = (float*)(ws + 0xB0000);   // 8x256
  float* sxpart = (float*)(ws + 1 * MB);    // 8x256x64 f32 = 512KB
  float* part   = (float*)(ws + 2 * MB);    // 32x256x256 f32 = 8MB
  unsigned short* Gbf  = (unsigned short*)(ws + 10 * MB);  // 1MB
  unsigned short* Ubf  = (unsigned short*)(ws + 11 * MB);  // 2MB
  float* logits        = (float*)(ws + 13 * MB);           // 2MB
  unsigned short* Abf  = (unsigned short*)(ws + 15 * MB);  // 1MB
  unsigned short* Y1   = (unsigned short*)(ws + 16 * MB);  // 1MB
  float* FT            = (float*)(ws + 17 * MB);           // 2MB
  unsigned short* Fbf  = (unsigned short*)(ws + 19 * MB);  // 1MB
  unsigned short* xbf  = (unsigned short*)(ws + 20 * MB);  // 16MB
  unsigned short* xT   = (unsigned short*)(ws + 36 * MB);  // 16MB
  if (ws_size < 52 * MB) return;

  // weights -> bf16 (+ Wv^T)
  cvt_bf_k<<<192, 256, 0, stream>>>(qkv_w, qkvw_bf, 768 * 256 / 4);
  cvt_bf_k<<<64, 256, 0, stream>>>(proj_w, pw_bf, 256 * 256 / 4);
  cvt_t_k<<<dim3(4, 4), 256, 0, stream>>>(qkv_w + 512 * 256, wvt_bf);

  // x -> xbf, xT, sx partials
  xprep_k<<<dim3(64, 4, 8), 256, 0, stream>>>(x, xbf, xT, sxpart);

  // Sxx = X X^T  (4 n-slices of 1024)
  {
    NTArgs p{};
    p.A = xbf; p.abst = 1L << 20; p.lda = 4096;
    p.B = xbf; p.bbst = 1L << 20; p.ldb = 4096;
    p.K = 4096; p.zdiv = 4;
    p.outF = part; p.ostF = 65536; p.ldc = 256;
    nt64_k<EPI_F32><<<dim3(4, 4, 32), 256, 0, stream>>>(p);
  }

  // stats -> a,e,s,sx, ws
  stats_k<<<8, 256, 0, stream>>>(part, sxpart, gamma, beta, qkvw_bf,
                                 avec, evec, svec, sxvec, wsv);
  // G (bf16)
  gfill_k<<<dim3(16, 8), 256, 0, stream>>>(part, avec, evec, sxvec, Gbf);

  // U = [Wq;Wk] @ G   (G symmetric -> NT)
  {
    NTArgs p{};
    p.A = qkvw_bf; p.abst = 0; p.lda = 256;
    p.B = Gbf; p.bbst = 65536; p.ldb = 256;
    p.K = 256; p.zdiv = 1;
    p.outU = Ubf; p.ostU = 131072; p.ldc = 256;
    nt64_k<EPI_BF16><<<dim3(4, 8, 8), 256, 0, stream>>>(p);
  }

  // l2 scales
  scales_k<<<1024, 256, 0, stream>>>(Ubf, qkvw_bf, qkv_b, wsv, qsv);

  // logits = T * qs_i ks_j * (U_q . Wk + bias terms)
  {
    NTArgs p{};
    p.A = Ubf; p.abst = 131072; p.lda = 256;
    p.B = qkvw_bf + 256 * 256; p.bbst = 0; p.ldb = 256;
    p.K = 256; p.zdiv = 1;
    p.outF = logits; p.ostF = 65536; p.ldc = 256;
    p.qs = qsv; p.wsv = wsv; p.qkvb = qkv_b; p.temp = temp;
    nt64_k<EPI_LOGITS><<<dim3(4, 4, 8), 256, 0, stream>>>(p);
  }

  // softmax -> A (bf16)
  softmax_k<<<2048, 256, 0, stream>>>(logits, Abf);

  // Y1 = Wv^T A^T   (NT: A-op = Wv^T, B-op = A rows)
  {
    NTArgs p{};
    p.A = wvt_bf; p.abst = 0; p.lda = 256;
    p.B = Abf; p.bbst = 65536; p.ldb = 256;
    p.K = 256; p.zdiv = 1;
    p.outU = Y1; p.ostU = 65536; p.ldc = 256;
    nt64_k<EPI_BF16><<<dim3(4, 4, 8), 256, 0, stream>>>(p);
  }

  // F^T = Y1 @ Pw^T  (NT: B-op = Pw rows)
  {
    NTArgs p{};
    p.A = Y1; p.abst = 65536; p.lda = 256;
    p.B = pw_bf; p.bbst = 0; p.ldb = 256;
    p.K = 256; p.zdiv = 1;
    p.outF = FT; p.ostF = 65536; p.ldc = 256;
    nt64_k<EPI_F32><<<dim3(4, 4, 8), 256, 0, stream>>>(p);
  }

  // finalize: F~ = F * diag(a) (bf16), h~ = F e + Pw A bv + pb
  finalize_k<<<8, 256, 0, stream>>>(Abf, FT, avec, evec, qkv_b, proj_w, proj_b,
                                    Fbf, hvec);

  // out = F~ @ X + h~ + x
  {
    NTArgs p{};
    p.A = Fbf; p.abst = 65536; p.lda = 256;
    p.B = xT; p.bbst = 1L << 20; p.ldb = 256;
    p.K = 256; p.zdiv = 1;
    p.outF = out; p.ostF = 0; p.ldc = 4096;
    p.hvec = hvec; p.xres = x;
    nt64_k<EPI_OUT><<<dim3(64, 4, 8), 256, 0, stream>>>(p);
  }
}